// Round 1
// baseline (963.632 us; speedup 1.0000x reference)
//
#include <hip/hip_runtime.h>
#include <hip/hip_bf16.h>

#define NN 100000
#define IN_CH 128
#define HID 8
#define HEADS 8
#define HC 64  // HEADS*HID

// ---------------- CSR build ----------------

__global__ __launch_bounds__(256) void k_hist(const int* __restrict__ ei, int E, int ET,
                                              int* __restrict__ deg) {
    int t = blockIdx.x * 256 + threadIdx.x;
    if (t >= ET) return;
    int d = (t < E) ? ei[E + t] : (t - E);  // self-loop for t >= E
    atomicAdd(&deg[d], 1);
}

__global__ __launch_bounds__(256) void k_scan_a(const int* __restrict__ deg, int n,
                                                int* __restrict__ csum) {
    __shared__ int sd[256];
    int t = threadIdx.x;
    int base = blockIdx.x * 2048;
    int s = 0;
#pragma unroll
    for (int i = 0; i < 8; ++i) {
        int gi = base + t * 8 + i;
        s += (gi < n) ? deg[gi] : 0;
    }
    sd[t] = s;
    __syncthreads();
    for (int off = 128; off > 0; off >>= 1) {
        if (t < off) sd[t] += sd[t + off];
        __syncthreads();
    }
    if (t == 0) csum[blockIdx.x] = sd[0];
}

__global__ void k_scan_b(int* csum, int nb) {
    if (threadIdx.x == 0) {
        int run = 0;
        for (int b = 0; b < nb; ++b) { int v = csum[b]; csum[b] = run; run += v; }
    }
}

__global__ __launch_bounds__(256) void k_scan_c(const int* __restrict__ deg, int n,
                                                const int* __restrict__ csum,
                                                int* __restrict__ row_ptr) {
    __shared__ int sd[256];
    int t = threadIdx.x;
    int base = blockIdx.x * 2048;
    int v[8];
    int tt = 0;
#pragma unroll
    for (int i = 0; i < 8; ++i) {
        int gi = base + t * 8 + i;
        v[i] = (gi < n) ? deg[gi] : 0;
        tt += v[i];
    }
    sd[t] = tt;
    __syncthreads();
    for (int off = 1; off < 256; off <<= 1) {
        int u = (t >= off) ? sd[t - off] : 0;
        __syncthreads();
        sd[t] += u;
        __syncthreads();
    }
    int excl = csum[blockIdx.x] + sd[t] - tt;  // exclusive prefix for this thread's chunk
#pragma unroll
    for (int i = 0; i < 8; ++i) {
        int gi = base + t * 8 + i;
        if (gi < n) row_ptr[gi] = excl;
        if (gi == n - 1) row_ptr[n] = excl + v[i];
        excl += v[i];
    }
}

__global__ __launch_bounds__(256) void k_scatter(const int* __restrict__ ei, int E, int ET,
                                                 const int* __restrict__ row_ptr,
                                                 int* __restrict__ cursor,
                                                 int* __restrict__ csr_src) {
    int t = blockIdx.x * 256 + threadIdx.x;
    if (t >= ET) return;
    int s, d;
    if (t < E) { s = ei[t]; d = ei[E + t]; } else { s = t - E; d = t - E; }
    int pos = atomicAdd(&cursor[d], 1);
    csr_src[row_ptr[d] + pos] = s;
}

// ---------------- Layer 1: h1 = x@W1, alpha_src/dst ----------------
// block = 256 threads = 4 waves; each wave handles 4 rows; lane: row=(lane>>4), c0=4*(lane&15)

__global__ __launch_bounds__(256) void k_gemm1(const float* __restrict__ x,
                                               const float* __restrict__ W1,
                                               const float* __restrict__ aS,
                                               const float* __restrict__ aD,
                                               float* __restrict__ h1,
                                               float* __restrict__ asrc1,
                                               float* __restrict__ adst1) {
    __shared__ float wl[IN_CH * HC];  // 32 KB
    int tid = threadIdx.x;
    {
        const float4* Wg4 = (const float4*)W1;
        float4* wl4 = (float4*)wl;
#pragma unroll
        for (int i = 0; i < 8; ++i) wl4[tid + i * 256] = Wg4[tid + i * 256];
    }
    __syncthreads();
    int lane = tid & 63;
    int row = blockIdx.x * 16 + (tid >> 6) * 4 + (lane >> 4);
    int c0 = (lane & 15) * 4;
    const float4* xr = (const float4*)(x + (size_t)row * IN_CH);
    float4 acc = make_float4(0.f, 0.f, 0.f, 0.f);
#pragma unroll 4
    for (int kq = 0; kq < IN_CH / 4; ++kq) {
        float4 xv = xr[kq];
        const float4* wrow = (const float4*)(wl + (kq * 4) * HC + c0);
        float4 w0 = wrow[0];
        float4 w1 = wrow[HC / 4];
        float4 w2 = wrow[2 * (HC / 4)];
        float4 w3 = wrow[3 * (HC / 4)];
        acc.x += xv.x * w0.x + xv.y * w1.x + xv.z * w2.x + xv.w * w3.x;
        acc.y += xv.x * w0.y + xv.y * w1.y + xv.z * w2.y + xv.w * w3.y;
        acc.z += xv.x * w0.z + xv.y * w1.z + xv.z * w2.z + xv.w * w3.z;
        acc.w += xv.x * w0.w + xv.y * w1.w + xv.z * w2.w + xv.w * w3.w;
    }
    *(float4*)(h1 + (size_t)row * HC + c0) = acc;
    int head = (lane & 15) >> 1;
    int cl = c0 & 7;
    const float* as = aS + head * 8 + cl;
    const float* ad = aD + head * 8 + cl;
    float ps = acc.x * as[0] + acc.y * as[1] + acc.z * as[2] + acc.w * as[3];
    float pd = acc.x * ad[0] + acc.y * ad[1] + acc.z * ad[2] + acc.w * ad[3];
    ps += __shfl_xor(ps, 1, 64);
    pd += __shfl_xor(pd, 1, 64);
    if ((lane & 1) == 0) {
        asrc1[row * 8 + head] = ps;
        adst1[row * 8 + head] = pd;
    }
}

// ---------------- Layer 1 aggregation: one wave per dst node ----------------

__global__ __launch_bounds__(256) void k_agg1(const int* __restrict__ row_ptr,
                                              const int* __restrict__ csr,
                                              const float* __restrict__ asrc1,
                                              const float* __restrict__ adst1,
                                              const float* __restrict__ h1,
                                              const float* __restrict__ b1,
                                              float* __restrict__ hrelu) {
    int tid = threadIdx.x;
    int lane = tid & 63;
    int n = blockIdx.x * 4 + (tid >> 6);
    int hl = lane >> 3;
    float adst = adst1[n * 8 + hl];
    int beg = row_ptr[n], end = row_ptr[n + 1];
    float m = -__builtin_inff();
    for (int j = beg; j < end; ++j) {
        int s = csr[j];
        float e = asrc1[s * 8 + hl] + adst;
        e = (e > 0.f) ? e : 0.2f * e;
        m = fmaxf(m, e);
    }
    float z = 0.f, acc = 0.f;
    for (int j = beg; j < end; ++j) {
        int s = csr[j];
        float e = asrc1[s * 8 + hl] + adst;
        e = (e > 0.f) ? e : 0.2f * e;
        float p = __expf(e - m);
        z += p;
        acc += p * h1[(size_t)s * HC + lane];
    }
    float o = acc / (z + 1e-16f) + b1[lane];
    hrelu[(size_t)n * HC + lane] = fmaxf(o, 0.f);
}

// ---------------- Layer 2: h2 = hrelu@W2, alpha2 ----------------
// wave: 8 rows x 8 cols

__global__ __launch_bounds__(256) void k_gemm2(const float* __restrict__ hrelu,
                                               const float* __restrict__ W2,
                                               const float* __restrict__ aS2,
                                               const float* __restrict__ aD2,
                                               float* __restrict__ h2,
                                               float* __restrict__ asrc2,
                                               float* __restrict__ adst2) {
    __shared__ float wl[HC * HID];  // 2 KB
    int tid = threadIdx.x;
    if (tid < 128) ((float4*)wl)[tid] = ((const float4*)W2)[tid];
    __syncthreads();
    int lane = tid & 63;
    int row = blockIdx.x * 32 + (tid >> 6) * 8 + (lane >> 3);
    int c = lane & 7;
    const float4* hr4 = (const float4*)(hrelu + (size_t)row * HC);
    float acc = 0.f;
#pragma unroll
    for (int kq = 0; kq < HC / 4; ++kq) {
        float4 hv = hr4[kq];
        acc += hv.x * wl[(kq * 4 + 0) * HID + c] + hv.y * wl[(kq * 4 + 1) * HID + c] +
               hv.z * wl[(kq * 4 + 2) * HID + c] + hv.w * wl[(kq * 4 + 3) * HID + c];
    }
    h2[(size_t)row * HID + c] = acc;
    float ps = acc * aS2[c];
    float pd = acc * aD2[c];
    ps += __shfl_xor(ps, 1, 64); ps += __shfl_xor(ps, 2, 64); ps += __shfl_xor(ps, 4, 64);
    pd += __shfl_xor(pd, 1, 64); pd += __shfl_xor(pd, 2, 64); pd += __shfl_xor(pd, 4, 64);
    if (c == 0) { asrc2[row] = ps; adst2[row] = pd; }
}

// ---------------- Layer 2 aggregation + classifier ----------------
// 8 lanes per node; 8 nodes per wave

__global__ __launch_bounds__(256) void k_agg2(const int* __restrict__ row_ptr,
                                              const int* __restrict__ csr,
                                              const float* __restrict__ asrc2,
                                              const float* __restrict__ adst2,
                                              const float* __restrict__ h2,
                                              const float* __restrict__ b2,
                                              const float* __restrict__ Wc,
                                              const float* __restrict__ bc,
                                              float* __restrict__ out) {
    int tid = threadIdx.x;
    int lane = tid & 63;
    int n = blockIdx.x * 32 + (tid >> 6) * 8 + (lane >> 3);
    int cl = lane & 7;
    float adst = adst2[n];
    int beg = row_ptr[n], end = row_ptr[n + 1];
    float m = -__builtin_inff();
    for (int j = beg; j < end; ++j) {
        float e = asrc2[csr[j]] + adst;
        e = (e > 0.f) ? e : 0.2f * e;
        m = fmaxf(m, e);
    }
    float z = 0.f, acc = 0.f;
    for (int j = beg; j < end; ++j) {
        int s = csr[j];
        float e = asrc2[s] + adst;
        e = (e > 0.f) ? e : 0.2f * e;
        float p = __expf(e - m);
        z += p;
        acc += p * h2[(size_t)s * HID + cl];
    }
    float emb = acc / (z + 1e-16f) + b2[cl];
    out[(size_t)n * HID + cl] = emb;
    float t0 = emb * Wc[cl * 2 + 0];
    float t1 = emb * Wc[cl * 2 + 1];
    t0 += __shfl_xor(t0, 1, 64); t0 += __shfl_xor(t0, 2, 64); t0 += __shfl_xor(t0, 4, 64);
    t1 += __shfl_xor(t1, 1, 64); t1 += __shfl_xor(t1, 2, 64); t1 += __shfl_xor(t1, 4, 64);
    if (cl == 0) {
        out[(size_t)NN * HID + n * 2 + 0] = t0 + bc[0];
        out[(size_t)NN * HID + n * 2 + 1] = t1 + bc[1];
    }
}

// ---------------- launch ----------------

extern "C" void kernel_launch(void* const* d_in, const int* in_sizes, int n_in,
                              void* d_out, int out_size, void* d_ws, size_t ws_size,
                              hipStream_t stream) {
    const float* x  = (const float*)d_in[0];
    const int*   ei = (const int*)d_in[1];
    const float* W1 = (const float*)d_in[2];
    const float* aS = (const float*)d_in[3];
    const float* aD = (const float*)d_in[4];
    const float* b1 = (const float*)d_in[5];
    const float* W2 = (const float*)d_in[6];
    const float* aS2 = (const float*)d_in[7];
    const float* aD2 = (const float*)d_in[8];
    const float* b2 = (const float*)d_in[9];
    const float* Wc = (const float*)d_in[10];
    const float* bc = (const float*)d_in[11];

    int E = in_sizes[1] / 2;
    int N = NN;
    int ET = E + N;

    char* p = (char*)d_ws;
    auto alloc = [&](size_t bytes) -> char* {
        char* r = p;
        p += (bytes + 255) & ~(size_t)255;
        return r;
    };
    float* h1     = (float*)alloc((size_t)N * HC * 4);
    float* hrelu  = (float*)alloc((size_t)N * HC * 4);
    float* asrc1  = (float*)alloc((size_t)N * 8 * 4);
    float* adst1  = (float*)alloc((size_t)N * 8 * 4);
    float* h2     = (float*)alloc((size_t)N * HID * 4);
    float* asrc2  = (float*)alloc((size_t)N * 4);
    float* adst2  = (float*)alloc((size_t)N * 4);
    int*   deg    = (int*)alloc((size_t)N * 4);
    int*   row_ptr= (int*)alloc((size_t)(N + 1) * 4);
    int*   cursor = (int*)alloc((size_t)N * 4);
    int*   csum   = (int*)alloc(256 * 4);
    int*   csr    = (int*)alloc((size_t)ET * 4);

    hipMemsetAsync(deg, 0, (size_t)N * 4, stream);
    hipMemsetAsync(cursor, 0, (size_t)N * 4, stream);

    int eb = (ET + 255) / 256;
    k_hist<<<eb, 256, 0, stream>>>(ei, E, ET, deg);
    int nch = (N + 2047) / 2048;
    k_scan_a<<<nch, 256, 0, stream>>>(deg, N, csum);
    k_scan_b<<<1, 64, 0, stream>>>(csum, nch);
    k_scan_c<<<nch, 256, 0, stream>>>(deg, N, csum, row_ptr);
    k_scatter<<<eb, 256, 0, stream>>>(ei, E, ET, row_ptr, cursor, csr);

    k_gemm1<<<N / 16, 256, 0, stream>>>(x, W1, aS, aD, h1, asrc1, adst1);
    k_agg1<<<N / 4, 256, 0, stream>>>(row_ptr, csr, asrc1, adst1, h1, b1, hrelu);
    k_gemm2<<<N / 32, 256, 0, stream>>>(hrelu, W2, aS2, aD2, h2, asrc2, adst2);
    k_agg2<<<N / 32, 256, 0, stream>>>(row_ptr, csr, asrc2, adst2, h2, b2, Wc, bc,
                                       (float*)d_out);
}

// Round 2
// 613.276 us; speedup vs baseline: 1.5713x; 1.5713x over previous
//
#include <hip/hip_runtime.h>
#include <hip/hip_bf16.h>

#define NN 100000
#define IN_CH 128
#define HID 8
#define HEADS 8
#define HC 64  // HEADS*HID

// ---------------- CSR build ----------------

__global__ __launch_bounds__(256) void k_hist(const int* __restrict__ ei, int E, int ET,
                                              int* __restrict__ deg) {
    int t = blockIdx.x * 256 + threadIdx.x;
    if (t >= ET) return;
    int d = (t < E) ? ei[E + t] : (t - E);  // self-loop for t >= E
    atomicAdd(&deg[d], 1);
}

__global__ __launch_bounds__(256) void k_scan_a(const int* __restrict__ deg, int n,
                                                int* __restrict__ csum) {
    __shared__ int sd[256];
    int t = threadIdx.x;
    int base = blockIdx.x * 2048;
    int s = 0;
#pragma unroll
    for (int i = 0; i < 8; ++i) {
        int gi = base + t * 8 + i;
        s += (gi < n) ? deg[gi] : 0;
    }
    sd[t] = s;
    __syncthreads();
    for (int off = 128; off > 0; off >>= 1) {
        if (t < off) sd[t] += sd[t + off];
        __syncthreads();
    }
    if (t == 0) csum[blockIdx.x] = sd[0];
}

__global__ void k_scan_b(int* csum, int nb) {
    if (threadIdx.x == 0) {
        int run = 0;
        for (int b = 0; b < nb; ++b) { int v = csum[b]; csum[b] = run; run += v; }
    }
}

__global__ __launch_bounds__(256) void k_scan_c(const int* __restrict__ deg, int n,
                                                const int* __restrict__ csum,
                                                int* __restrict__ row_ptr) {
    __shared__ int sd[256];
    int t = threadIdx.x;
    int base = blockIdx.x * 2048;
    int v[8];
    int tt = 0;
#pragma unroll
    for (int i = 0; i < 8; ++i) {
        int gi = base + t * 8 + i;
        v[i] = (gi < n) ? deg[gi] : 0;
        tt += v[i];
    }
    sd[t] = tt;
    __syncthreads();
    for (int off = 1; off < 256; off <<= 1) {
        int u = (t >= off) ? sd[t - off] : 0;
        __syncthreads();
        sd[t] += u;
        __syncthreads();
    }
    int excl = csum[blockIdx.x] + sd[t] - tt;
#pragma unroll
    for (int i = 0; i < 8; ++i) {
        int gi = base + t * 8 + i;
        if (gi < n) row_ptr[gi] = excl;
        if (gi == n - 1) row_ptr[n] = excl + v[i];
        excl += v[i];
    }
}

__global__ __launch_bounds__(256) void k_scatter(const int* __restrict__ ei, int E, int ET,
                                                 const int* __restrict__ row_ptr,
                                                 int* __restrict__ cursor,
                                                 int* __restrict__ csr_src) {
    int t = blockIdx.x * 256 + threadIdx.x;
    if (t >= ET) return;
    int s, d;
    if (t < E) { s = ei[t]; d = ei[E + t]; } else { s = t - E; d = t - E; }
    int pos = atomicAdd(&cursor[d], 1);
    csr_src[row_ptr[d] + pos] = s;
}

// ---------------- Layer 1: h1 = x@W1, alpha_src/dst ----------------

__global__ __launch_bounds__(256) void k_gemm1(const float* __restrict__ x,
                                               const float* __restrict__ W1,
                                               const float* __restrict__ aS,
                                               const float* __restrict__ aD,
                                               float* __restrict__ h1,
                                               float* __restrict__ asrc1,
                                               float* __restrict__ adst1) {
    __shared__ float wl[IN_CH * HC];  // 32 KB
    int tid = threadIdx.x;
    {
        const float4* Wg4 = (const float4*)W1;
        float4* wl4 = (float4*)wl;
#pragma unroll
        for (int i = 0; i < 8; ++i) wl4[tid + i * 256] = Wg4[tid + i * 256];
    }
    __syncthreads();
    int lane = tid & 63;
    int row = blockIdx.x * 16 + (tid >> 6) * 4 + (lane >> 4);
    int c0 = (lane & 15) * 4;
    const float4* xr = (const float4*)(x + (size_t)row * IN_CH);
    float4 acc = make_float4(0.f, 0.f, 0.f, 0.f);
#pragma unroll 4
    for (int kq = 0; kq < IN_CH / 4; ++kq) {
        float4 xv = xr[kq];
        const float4* wrow = (const float4*)(wl + (kq * 4) * HC + c0);
        float4 w0 = wrow[0];
        float4 w1 = wrow[HC / 4];
        float4 w2 = wrow[2 * (HC / 4)];
        float4 w3 = wrow[3 * (HC / 4)];
        acc.x += xv.x * w0.x + xv.y * w1.x + xv.z * w2.x + xv.w * w3.x;
        acc.y += xv.x * w0.y + xv.y * w1.y + xv.z * w2.y + xv.w * w3.y;
        acc.z += xv.x * w0.z + xv.y * w1.z + xv.z * w2.z + xv.w * w3.z;
        acc.w += xv.x * w0.w + xv.y * w1.w + xv.z * w2.w + xv.w * w3.w;
    }
    *(float4*)(h1 + (size_t)row * HC + c0) = acc;
    int head = (lane & 15) >> 1;
    int cl = c0 & 7;
    const float* as = aS + head * 8 + cl;
    const float* ad = aD + head * 8 + cl;
    float ps = acc.x * as[0] + acc.y * as[1] + acc.z * as[2] + acc.w * as[3];
    float pd = acc.x * ad[0] + acc.y * ad[1] + acc.z * ad[2] + acc.w * ad[3];
    ps += __shfl_xor(ps, 1, 64);
    pd += __shfl_xor(pd, 1, 64);
    if ((lane & 1) == 0) {
        asrc1[row * 8 + head] = ps;
        adst1[row * 8 + head] = pd;
    }
}

// ---------------- Layer 1 aggregation: one wave per node, 4 edge-slots x 16 lanes,
// single-pass online softmax ----------------

__global__ __launch_bounds__(256) void k_agg1(const int* __restrict__ row_ptr,
                                              const int* __restrict__ csr,
                                              const float* __restrict__ asrc1,
                                              const float* __restrict__ adst1,
                                              const float* __restrict__ h1,
                                              const float* __restrict__ b1,
                                              float* __restrict__ hrelu) {
    int tid = threadIdx.x;
    int lane = tid & 63;
    int n = blockIdx.x * 4 + (tid >> 6);
    int slot = lane >> 4;  // 0..3
    int sl = lane & 15;    // 0..15
    int c0 = sl * 4;
    int head = sl >> 1;
    float adst = adst1[n * 8 + head];
    int beg = row_ptr[n], end = row_ptr[n + 1];
    int nit = (end - beg + 3) >> 2;
    float m = -3.0e38f, z = 0.f;
    float4 acc = make_float4(0.f, 0.f, 0.f, 0.f);
    int j = beg + slot;
    int s_cur = (j < end) ? csr[j] : -1;
    for (int it = 0; it < nit; ++it) {
        int jn = j + 4;
        int s_nxt = (jn < end) ? csr[jn] : -1;
        if (s_cur >= 0) {
            float e = asrc1[s_cur * 8 + head] + adst;
            e = (e > 0.f) ? e : 0.2f * e;
            float4 hv = *(const float4*)(h1 + (size_t)s_cur * HC + c0);
            float mn = fmaxf(m, e);
            float rs = __expf(m - mn);
            float p = __expf(e - mn);
            m = mn;
            z = z * rs + p;
            acc.x = acc.x * rs + p * hv.x;
            acc.y = acc.y * rs + p * hv.y;
            acc.z = acc.z * rs + p * hv.z;
            acc.w = acc.w * rs + p * hv.w;
        }
        j = jn;
        s_cur = s_nxt;
    }
    // merge the 4 slots (partners at lane^16, lane^32)
#pragma unroll
    for (int off = 16; off <= 32; off <<= 1) {
        float mo = __shfl_xor(m, off, 64);
        float zo = __shfl_xor(z, off, 64);
        float ax = __shfl_xor(acc.x, off, 64);
        float ay = __shfl_xor(acc.y, off, 64);
        float az = __shfl_xor(acc.z, off, 64);
        float aw = __shfl_xor(acc.w, off, 64);
        float mn = fmaxf(m, mo);
        float rs = __expf(m - mn);
        float ro = __expf(mo - mn);
        m = mn;
        z = z * rs + zo * ro;
        acc.x = acc.x * rs + ax * ro;
        acc.y = acc.y * rs + ay * ro;
        acc.z = acc.z * rs + az * ro;
        acc.w = acc.w * rs + aw * ro;
    }
    if (slot == 0) {
        const float4 bv = *(const float4*)(b1 + c0);
        float inv = 1.f / (z + 1e-16f);
        float4 o;
        o.x = fmaxf(acc.x * inv + bv.x, 0.f);
        o.y = fmaxf(acc.y * inv + bv.y, 0.f);
        o.z = fmaxf(acc.z * inv + bv.z, 0.f);
        o.w = fmaxf(acc.w * inv + bv.w, 0.f);
        *(float4*)(hrelu + (size_t)n * HC + c0) = o;
    }
}

// ---------------- Layer 2: h2 = hrelu@W2, alpha2 ----------------

__global__ __launch_bounds__(256) void k_gemm2(const float* __restrict__ hrelu,
                                               const float* __restrict__ W2,
                                               const float* __restrict__ aS2,
                                               const float* __restrict__ aD2,
                                               float* __restrict__ h2,
                                               float* __restrict__ asrc2,
                                               float* __restrict__ adst2) {
    __shared__ float wl[HC * HID];  // 2 KB
    int tid = threadIdx.x;
    if (tid < 128) ((float4*)wl)[tid] = ((const float4*)W2)[tid];
    __syncthreads();
    int lane = tid & 63;
    int row = blockIdx.x * 32 + (tid >> 6) * 8 + (lane >> 3);
    int c = lane & 7;
    const float4* hr4 = (const float4*)(hrelu + (size_t)row * HC);
    float acc = 0.f;
#pragma unroll
    for (int kq = 0; kq < HC / 4; ++kq) {
        float4 hv = hr4[kq];
        acc += hv.x * wl[(kq * 4 + 0) * HID + c] + hv.y * wl[(kq * 4 + 1) * HID + c] +
               hv.z * wl[(kq * 4 + 2) * HID + c] + hv.w * wl[(kq * 4 + 3) * HID + c];
    }
    h2[(size_t)row * HID + c] = acc;
    float ps = acc * aS2[c];
    float pd = acc * aD2[c];
    ps += __shfl_xor(ps, 1, 64); ps += __shfl_xor(ps, 2, 64); ps += __shfl_xor(ps, 4, 64);
    pd += __shfl_xor(pd, 1, 64); pd += __shfl_xor(pd, 2, 64); pd += __shfl_xor(pd, 4, 64);
    if (c == 0) { asrc2[row] = ps; adst2[row] = pd; }
}

// ---------------- Layer 2 aggregation + classifier: one wave per node,
// 8 edge-slots x 8 lanes, single-pass online softmax ----------------

__global__ __launch_bounds__(256) void k_agg2(const int* __restrict__ row_ptr,
                                              const int* __restrict__ csr,
                                              const float* __restrict__ asrc2,
                                              const float* __restrict__ adst2,
                                              const float* __restrict__ h2,
                                              const float* __restrict__ b2,
                                              const float* __restrict__ Wc,
                                              const float* __restrict__ bc,
                                              float* __restrict__ out) {
    int tid = threadIdx.x;
    int lane = tid & 63;
    int n = blockIdx.x * 4 + (tid >> 6);
    int slot = lane >> 3;  // 0..7
    int sl = lane & 7;     // channel
    float adst = adst2[n];
    int beg = row_ptr[n], end = row_ptr[n + 1];
    int nit = (end - beg + 7) >> 3;
    float m = -3.0e38f, z = 0.f, acc = 0.f;
    int j = beg + slot;
    int s_cur = (j < end) ? csr[j] : -1;
    for (int it = 0; it < nit; ++it) {
        int jn = j + 8;
        int s_nxt = (jn < end) ? csr[jn] : -1;
        if (s_cur >= 0) {
            float e = asrc2[s_cur] + adst;
            e = (e > 0.f) ? e : 0.2f * e;
            float hv = h2[(size_t)s_cur * HID + sl];
            float mn = fmaxf(m, e);
            float rs = __expf(m - mn);
            float p = __expf(e - mn);
            m = mn;
            z = z * rs + p;
            acc = acc * rs + p * hv;
        }
        j = jn;
        s_cur = s_nxt;
    }
#pragma unroll
    for (int off = 8; off <= 32; off <<= 1) {
        float mo = __shfl_xor(m, off, 64);
        float zo = __shfl_xor(z, off, 64);
        float ao = __shfl_xor(acc, off, 64);
        float mn = fmaxf(m, mo);
        float rs = __expf(m - mn);
        float ro = __expf(mo - mn);
        m = mn;
        z = z * rs + zo * ro;
        acc = acc * rs + ao * ro;
    }
    float emb = acc / (z + 1e-16f) + b2[sl];
    if (slot == 0) out[(size_t)n * HID + sl] = emb;
    float t0 = emb * Wc[sl * 2 + 0];
    float t1 = emb * Wc[sl * 2 + 1];
    t0 += __shfl_xor(t0, 1, 64); t0 += __shfl_xor(t0, 2, 64); t0 += __shfl_xor(t0, 4, 64);
    t1 += __shfl_xor(t1, 1, 64); t1 += __shfl_xor(t1, 2, 64); t1 += __shfl_xor(t1, 4, 64);
    if (lane == 0) {
        out[(size_t)NN * HID + n * 2 + 0] = t0 + bc[0];
        out[(size_t)NN * HID + n * 2 + 1] = t1 + bc[1];
    }
}

// ---------------- launch ----------------

extern "C" void kernel_launch(void* const* d_in, const int* in_sizes, int n_in,
                              void* d_out, int out_size, void* d_ws, size_t ws_size,
                              hipStream_t stream) {
    const float* x  = (const float*)d_in[0];
    const int*   ei = (const int*)d_in[1];
    const float* W1 = (const float*)d_in[2];
    const float* aS = (const float*)d_in[3];
    const float* aD = (const float*)d_in[4];
    const float* b1 = (const float*)d_in[5];
    const float* W2 = (const float*)d_in[6];
    const float* aS2 = (const float*)d_in[7];
    const float* aD2 = (const float*)d_in[8];
    const float* b2 = (const float*)d_in[9];
    const float* Wc = (const float*)d_in[10];
    const float* bc = (const float*)d_in[11];

    int E = in_sizes[1] / 2;
    int N = NN;
    int ET = E + N;

    char* p = (char*)d_ws;
    auto alloc = [&](size_t bytes) -> char* {
        char* r = p;
        p += (bytes + 255) & ~(size_t)255;
        return r;
    };
    float* h1     = (float*)alloc((size_t)N * HC * 4);
    float* hrelu  = (float*)alloc((size_t)N * HC * 4);
    float* asrc1  = (float*)alloc((size_t)N * 8 * 4);
    float* adst1  = (float*)alloc((size_t)N * 8 * 4);
    float* h2     = (float*)alloc((size_t)N * HID * 4);
    float* asrc2  = (float*)alloc((size_t)N * 4);
    float* adst2  = (float*)alloc((size_t)N * 4);
    int*   deg    = (int*)alloc((size_t)N * 4);
    int*   row_ptr= (int*)alloc((size_t)(N + 1) * 4);
    int*   cursor = (int*)alloc((size_t)N * 4);
    int*   csum   = (int*)alloc(256 * 4);
    int*   csr    = (int*)alloc((size_t)ET * 4);

    hipMemsetAsync(deg, 0, (size_t)N * 4, stream);
    hipMemsetAsync(cursor, 0, (size_t)N * 4, stream);

    int eb = (ET + 255) / 256;
    k_hist<<<eb, 256, 0, stream>>>(ei, E, ET, deg);
    int nch = (N + 2047) / 2048;
    k_scan_a<<<nch, 256, 0, stream>>>(deg, N, csum);
    k_scan_b<<<1, 64, 0, stream>>>(csum, nch);
    k_scan_c<<<nch, 256, 0, stream>>>(deg, N, csum, row_ptr);
    k_scatter<<<eb, 256, 0, stream>>>(ei, E, ET, row_ptr, cursor, csr);

    k_gemm1<<<N / 16, 256, 0, stream>>>(x, W1, aS, aD, h1, asrc1, adst1);
    k_agg1<<<N / 4, 256, 0, stream>>>(row_ptr, csr, asrc1, adst1, h1, b1, hrelu);
    k_gemm2<<<N / 32, 256, 0, stream>>>(hrelu, W2, aS2, aD2, h2, asrc2, adst2);
    k_agg2<<<N / 4, 256, 0, stream>>>(row_ptr, csr, asrc2, adst2, h2, b2, Wc, bc,
                                      (float*)d_out);
}